// Round 7
// baseline (1775.098 us; speedup 1.0000x reference)
//
#include <hip/hip_runtime.h>
#include <math.h>

#define MAX_ITER 20
#define EPS_W 1e-3f
#define CLAMP_MIN 1e-4f
#define CLAMP_MAX 1e4f

#define E 16
#define CGBLK 256
#define CHUNK (E * CGBLK)  // 4096 elements per block; bpb = K/CHUNK = 32

__device__ __forceinline__ float sp_w(float u) {
    float sp = fmaxf(u, 0.f) + log1pf(expf(-fabsf(u)));
    float w = sp + EPS_W;
    return fminf(fmaxf(w, CLAMP_MIN), CLAMP_MAX);
}
__device__ __forceinline__ float nn(float x) { return (x == x) ? x : 0.f; }

// SYSTEM-scope relaxed atomics: lower to cache-bypassing (sc0 sc1) accesses
// that hit the coherence point directly — no stale L1/L2, no buffer_inv/wbl2.
__device__ __forceinline__ float sys_ldf(const float* p) {
    return __hip_atomic_load(p, __ATOMIC_RELAXED, __HIP_MEMORY_SCOPE_SYSTEM);
}
__device__ __forceinline__ void sys_stf(float* p, float v) {
    __hip_atomic_store(p, v, __ATOMIC_RELAXED, __HIP_MEMORY_SCOPE_SYSTEM);
}
__device__ __forceinline__ unsigned long long sys_ld64(const unsigned long long* p) {
    return __hip_atomic_load(p, __ATOMIC_RELAXED, __HIP_MEMORY_SCOPE_SYSTEM);
}
__device__ __forceinline__ unsigned long long sys_ld64_acq(const unsigned long long* p) {
    return __hip_atomic_load(p, __ATOMIC_ACQUIRE, __HIP_MEMORY_SCOPE_SYSTEM);
}
__device__ __forceinline__ void sys_st64(unsigned long long* p, unsigned long long v) {
    __hip_atomic_store(p, v, __ATOMIC_RELAXED, __HIP_MEMORY_SCOPE_SYSTEM);
}

// result valid on threadIdx.x == 0 only; block must be 256 threads (4 waves)
__device__ __forceinline__ float blockReduceSum(float v) {
    #pragma unroll
    for (int off = 32; off > 0; off >>= 1) v += __shfl_down(v, off, 64);
    __shared__ float smem[4];
    int lane = threadIdx.x & 63, wid = threadIdx.x >> 6;
    if (lane == 0) smem[wid] = v;
    __syncthreads();
    float r = 0.f;
    if (threadIdx.x == 0) r = smem[0] + smem[1] + smem[2] + smem[3];
    return r;
}

// Fused per-batch reduction + barrier. Self-validating {gen|payload} words,
// all system-scope (cache-bypassing). No fences in the common path: the
// producer-side ordering (halo stores -> arrival publish) is given by the
// compiler's s_waitcnt vmcnt(0) before s_barrier inside blockReduceSum.
__device__ float round_sum(float partial, unsigned gen,
                           unsigned long long* __restrict__ slotA,
                           unsigned long long* __restrict__ slotR,
                           int blk, int bbase, int bpb, int relIdx, bool leader) {
    __shared__ float bsum;
    float bs = blockReduceSum(partial);          // valid on tid 0
    const int tid = threadIdx.x;
    if (tid == 0)
        sys_st64(&slotA[blk], ((unsigned long long)gen << 32) | __float_as_uint(bs));
    if (leader) {
        float lp = 0.f;
        if (tid < bpb) {
            unsigned long long v; int s = 0;
            for (;;) {
                v = sys_ld64(&slotA[bbase + tid]);
                if ((unsigned)(v >> 32) >= gen) break;
                if ((++s & 63) == 0) {           // livelock insurance only
                    v = sys_ld64_acq(&slotA[bbase + tid]);
                    if ((unsigned)(v >> 32) >= gen) break;
                }
                __builtin_amdgcn_s_sleep(1);
            }
            lp = __uint_as_float((unsigned)v);
        }
        #pragma unroll
        for (int off = 16; off > 0; off >>= 1) lp += __shfl_down(lp, off, 32);
        if (tid == 0) {
            sys_st64(&slotR[relIdx], ((unsigned long long)gen << 32) | __float_as_uint(lp));
            bsum = lp;
        }
    } else {
        if (tid == 0) {
            unsigned long long v; int s = 0;
            for (;;) {
                v = sys_ld64(&slotR[relIdx]);
                if ((unsigned)(v >> 32) >= gen) break;
                if ((++s & 63) == 0) {
                    v = sys_ld64_acq(&slotR[relIdx]);
                    if ((unsigned)(v >> 32) >= gen) break;
                }
                __builtin_amdgcn_s_sleep(1);
            }
            bsum = __uint_as_float((unsigned)v);
        }
    }
    __syncthreads();
    return bsum;
}

__global__ __launch_bounds__(256) void k_scatter(const int* __restrict__ idx,
                                                 int* __restrict__ pos, int K) {
    int k = blockIdx.x * 256 + threadIdx.x;
    if (k < K) pos[idx[k]] = k;
}

__global__ __launch_bounds__(256) void k_w(const float* __restrict__ u,
                                           float* __restrict__ w, int total4) {
    int t = blockIdx.x * 256 + threadIdx.x;
    if (t >= total4) return;
    float4 uu = reinterpret_cast<const float4*>(u)[t];
    float4 ww;
    ww.x = sp_w(uu.x); ww.y = sp_w(uu.y); ww.z = sp_w(uu.z); ww.w = sp_w(uu.w);
    reinterpret_cast<float4*>(w)[t] = ww;
}

// Persistent CG: init + 20 iterations, all state in registers.
// (Kp)[k] = dg[k]*p[k] - cl[k]*p[k-1] - cl[k+1]*p[k+1]
__global__ __attribute__((amdgpu_flat_work_group_size(256, 256),
                          amdgpu_waves_per_eu(2, 2)))
void k_cg_pers(
        const int* __restrict__ idx, const float* __restrict__ w_all,
        const float* __restrict__ x, float* __restrict__ v_out,
        unsigned long long* __restrict__ slotA,   // [nblk]
        unsigned long long* __restrict__ slotR,   // [B*16], padded per batch
        float* __restrict__ pbl, float* __restrict__ pbr,   // [2*nblk] parity dbuf
        float* __restrict__ rbl, float* __restrict__ rbr,   // [nblk]
        int n, int K, int B, int nblk) {
    const int blk = blockIdx.x, tid = threadIdx.x;
    const int bpb = K / CHUNK;                 // 32 blocks per batch
    const int b = blk / bpb;
    const int bbase = b * bpb;
    const int relIdx = b * 16;
    const bool leader = (blk == bbase);
    const bool first_blk = (blk == bbase);
    const bool last_blk  = (blk == bbase + bpb - 1);
    const int k0 = (blk - bbase) * CHUNK + tid * E;
    const int m = n - 1;
    const float* wb = w_all + (size_t)b * m;
    const float* xb = x + (size_t)b * n;

    // ---------- init: build dg, cl, rhs in registers ----------
    int jj[E + 2];
    #pragma unroll
    for (int t = 0; t < E + 2; ++t) {
        int k = k0 - 1 + t;
        jj[t] = (k >= 0 && k < K) ? idx[k] : -1000000;
    }
    float vv[E], rcg[E], p[E], kp[E], dgr[E], clr[E + 1];
    float s0 = 0.f;
    #pragma unroll
    for (int q = 0; q < E; ++q) {
        int j = jj[q + 1];
        bool la = (jj[q] == j - 1);
        bool ra = (jj[q + 2] == j + 1);
        float wl = 0.f, wr = 0.f;
        if (j >= 1)     { float w = wb[j - 1]; wl = w * w; }
        if (j <= n - 2) { float w = wb[j];     wr = w * w; }
        float rhs = 0.f;
        if (j >= 1 && !la)     rhs += wl * nn(xb[j - 1]);
        if (j <= n - 2 && !ra) rhs += wr * nn(xb[j + 1]);
        vv[q] = 0.f; rcg[q] = rhs; p[q] = rhs; kp[q] = 0.f;
        dgr[q] = wl + wr;
        clr[q] = la ? wl : 0.f;
        s0 += rhs * rhs;
    }
    {   // clr[E] = left coupling of element k0+E (first elem of next thread)
        float cl8 = 0.f;
        int j8 = jj[E + 1];
        if ((k0 + E) < K && jj[E] == j8 - 1) { float w = wb[j8 - 1]; cl8 = w * w; }
        clr[E] = cl8;
    }
    if (tid == 0)         { sys_stf(&rbl[blk], rcg[0]);     sys_stf(&pbl[blk], p[0]); }
    if (tid == CGBLK - 1) { sys_stf(&rbr[blk], rcg[E - 1]); sys_stf(&pbr[blk], p[E - 1]); }

    float rs_prev = 1.f;
    float rs_cur = round_sum(s0, 1u, slotA, slotR, blk, bbase, bpb, relIdx, leader);

    __shared__ float sLa[CGBLK], sRa[CGBLK];

    for (int it = 0; it < MAX_ITER; ++it) {
        // ---- phase A: p update, halos, Kp, p.Kp ----
        float beta = (it > 0) ? rs_cur / (rs_prev + 1e-30f) : 0.f;
        #pragma unroll
        for (int q = 0; q < E; ++q) p[q] = rcg[q] + beta * p[q];
        sLa[tid] = p[0]; sRa[tid] = p[E - 1];
        __syncthreads();
        int rslot = (it & 1) * nblk, wslot = ((it + 1) & 1) * nblk;
        float pl, pr;
        if (tid > 0) pl = sRa[tid - 1];
        else pl = first_blk ? 0.f
                            : (sys_ldf(&rbr[blk - 1]) + beta * sys_ldf(&pbr[rslot + blk - 1]));
        if (tid < CGBLK - 1) pr = sLa[tid + 1];
        else pr = last_blk ? 0.f
                           : (sys_ldf(&rbl[blk + 1]) + beta * sys_ldf(&pbl[rslot + blk + 1]));
        if (tid == 0)         sys_stf(&pbl[wslot + blk], p[0]);
        if (tid == CGBLK - 1) sys_stf(&pbr[wslot + blk], p[E - 1]);
        float dot = 0.f;
        #pragma unroll
        for (int q = 0; q < E; ++q) {
            float pm = (q == 0) ? pl : p[q - 1];
            float pp = (q == E - 1) ? pr : p[q + 1];
            kp[q] = dgr[q] * p[q] - clr[q] * pm - clr[q + 1] * pp;
            dot += p[q] * kp[q];
        }
        float pkp = round_sum(dot, 2u + 2u * it, slotA, slotR, blk, bbase, bpb, relIdx, leader);

        // ---- phase B: alpha, v/rcg update, ||r||^2 ----
        float alpha = rs_cur / (pkp + 1e-30f);
        float dot2 = 0.f;
        #pragma unroll
        for (int q = 0; q < E; ++q) {
            vv[q] += alpha * p[q];
            rcg[q] -= alpha * kp[q];
            dot2 += rcg[q] * rcg[q];
        }
        if (tid == 0)         sys_stf(&rbl[blk], rcg[0]);
        if (tid == CGBLK - 1) sys_stf(&rbr[blk], rcg[E - 1]);
        float rs_new = round_sum(dot2, 3u + 2u * it, slotA, slotR, blk, bbase, bpb, relIdx, leader);
        rs_prev = rs_cur; rs_cur = rs_new;
    }

    float* vb = v_out + (size_t)b * K + (size_t)(blk - bbase) * CHUNK + (size_t)tid * E;
    #pragma unroll
    for (int q4 = 0; q4 < E / 4; ++q4)
        reinterpret_cast<float4*>(vb)[q4] =
            make_float4(vv[4 * q4], vv[4 * q4 + 1], vv[4 * q4 + 2], vv[4 * q4 + 3]);
}

// ---- fallback path kernels (only used if cooperative launch fails) ----
__global__ __launch_bounds__(256) void k_init(const int* __restrict__ idx,
                                              const float* __restrict__ w_all,
                                              const float* __restrict__ x,
                                              float* __restrict__ rg,
                                              float* __restrict__ dg,
                                              float* __restrict__ cl,
                                              float* __restrict__ rs_arr,
                                              int n, int K) {
    int t = blockIdx.x * 256 + threadIdx.x;
    int g = t * 4;
    int b = g / K;
    int k = g - b * K;
    int m = n - 1;
    const float* wb = w_all + (size_t)b * m;
    const float* xb = x + (size_t)b * n;
    int4 i4 = reinterpret_cast<const int4*>(idx)[k / 4];
    int jj[6];
    jj[0] = (k > 0) ? idx[k - 1] : -1000000;
    jj[1] = i4.x; jj[2] = i4.y; jj[3] = i4.z; jj[4] = i4.w;
    jj[5] = (k + 4 < K) ? idx[k + 4] : -1000000;
    float rh[4], dgv[4], clv[4];
    float s0 = 0.f;
    #pragma unroll
    for (int q = 0; q < 4; ++q) {
        int j = jj[q + 1];
        bool la = (jj[q] == j - 1);
        bool ra = (jj[q + 2] == j + 1);
        float wl = 0.f, wr = 0.f;
        if (j >= 1)     { float w = wb[j - 1]; wl = w * w; }
        if (j <= n - 2) { float w = wb[j];     wr = w * w; }
        float rhs = 0.f;
        if (j >= 1 && !la)     rhs += wl * nn(xb[j - 1]);
        if (j <= n - 2 && !ra) rhs += wr * nn(xb[j + 1]);
        rh[q] = rhs; dgv[q] = wl + wr; clv[q] = la ? wl : 0.f;
        s0 += rhs * rhs;
    }
    reinterpret_cast<float4*>(rg)[t] = make_float4(rh[0], rh[1], rh[2], rh[3]);
    reinterpret_cast<float4*>(dg)[t] = make_float4(dgv[0], dgv[1], dgv[2], dgv[3]);
    reinterpret_cast<float4*>(cl)[t] = make_float4(clv[0], clv[1], clv[2], clv[3]);
    float s = blockReduceSum(s0);
    if (threadIdx.x == 0) atomicAdd(&rs_arr[b], s);
}

__global__ __launch_bounds__(256) void k_cg_a(const float* __restrict__ rg,
                                              const float* __restrict__ p_old,
                                              float* __restrict__ p_new,
                                              float* __restrict__ kp,
                                              const float* __restrict__ dg,
                                              const float* __restrict__ cl,
                                              const float* __restrict__ rs_arr,
                                              float* __restrict__ pkp_arr,
                                              int iter, int B, int K) {
    int t = blockIdx.x * 256 + threadIdx.x;
    int g = t * 4;
    int total = B * K;
    int b = g / K;
    float beta = (iter == 0) ? 0.f
               : rs_arr[iter * B + b] / (rs_arr[(iter - 1) * B + b] + 1e-30f);
    float4 rc = reinterpret_cast<const float4*>(rg)[t];
    float4 po = reinterpret_cast<const float4*>(p_old)[t];
    float4 dd = reinterpret_cast<const float4*>(dg)[t];
    float4 cc = reinterpret_cast<const float4*>(cl)[t];
    float rcm = (g > 0) ? rg[g - 1] : 0.f;
    float pom = (g > 0) ? p_old[g - 1] : 0.f;
    bool tail = (g + 4 < total);
    float rcp = tail ? rg[g + 4] : 0.f;
    float pop = tail ? p_old[g + 4] : 0.f;
    float ccp = tail ? cl[g + 4] : 0.f;
    float pn[6];
    pn[0] = rcm + beta * pom;
    pn[1] = rc.x + beta * po.x;
    pn[2] = rc.y + beta * po.y;
    pn[3] = rc.z + beta * po.z;
    pn[4] = rc.w + beta * po.w;
    pn[5] = rcp + beta * pop;
    float c[5] = {cc.x, cc.y, cc.z, cc.w, ccp};
    float d4[4] = {dd.x, dd.y, dd.z, dd.w};
    float kv[4];
    float dot = 0.f;
    #pragma unroll
    for (int i = 0; i < 4; ++i) {
        kv[i] = d4[i] * pn[i + 1] - c[i] * pn[i] - c[i + 1] * pn[i + 2];
        dot += pn[i + 1] * kv[i];
    }
    reinterpret_cast<float4*>(p_new)[t] = make_float4(pn[1], pn[2], pn[3], pn[4]);
    reinterpret_cast<float4*>(kp)[t]    = make_float4(kv[0], kv[1], kv[2], kv[3]);
    float s = blockReduceSum(dot);
    if (threadIdx.x == 0) atomicAdd(&pkp_arr[iter * B + b], s);
}

__global__ __launch_bounds__(256) void k_cg_b(float* __restrict__ v,
                                              float* __restrict__ rg,
                                              const float* __restrict__ p_new,
                                              const float* __restrict__ kp,
                                              float* __restrict__ rs_arr,
                                              const float* __restrict__ pkp_arr,
                                              int iter, int B, int K) {
    int t = blockIdx.x * 256 + threadIdx.x;
    int g = t * 4;
    int b = g / K;
    float alpha = rs_arr[iter * B + b] / (pkp_arr[iter * B + b] + 1e-30f);
    float4 pv = reinterpret_cast<const float4*>(p_new)[t];
    float4 kv = reinterpret_cast<const float4*>(kp)[t];
    float4 vv = reinterpret_cast<float4*>(v)[t];
    float4 rv = reinterpret_cast<float4*>(rg)[t];
    vv.x += alpha * pv.x; vv.y += alpha * pv.y; vv.z += alpha * pv.z; vv.w += alpha * pv.w;
    rv.x -= alpha * kv.x; rv.y -= alpha * kv.y; rv.z -= alpha * kv.z; rv.w -= alpha * kv.w;
    reinterpret_cast<float4*>(v)[t]  = vv;
    reinterpret_cast<float4*>(rg)[t] = rv;
    float dot = rv.x * rv.x + rv.y * rv.y + rv.z * rv.z + rv.w * rv.w;
    float s = blockReduceSum(dot);
    if (threadIdx.x == 0) atomicAdd(&rs_arr[(iter + 1) * B + b], s);
}

// final: r = D(x_known + scatter(v)), phi = sum w^2 r^2
__global__ __launch_bounds__(256) void k_final(const float* __restrict__ x,
                                               const float* __restrict__ w_out,
                                               const int* __restrict__ pos,
                                               const float* __restrict__ v,
                                               float* __restrict__ r_out,
                                               float* __restrict__ phi,
                                               int n, int K) {
    int m = n - 1;
    int b = blockIdx.y;
    int i0 = (blockIdx.x * 256 + threadIdx.x) * 4;
    const float* xb = x + (size_t)b * n;
    const float* wb = w_out + (size_t)b * m;
    const float* vb = v + (size_t)b * K;
    float* rb = r_out + (size_t)b * m;
    float sv[5];
    #pragma unroll
    for (int q = 0; q < 5; ++q) {
        int i = i0 + q;
        if (i <= m) {
            int p = pos[i];
            sv[q] = (p >= 0) ? vb[p] : nn(xb[i]);
        } else sv[q] = 0.f;
    }
    float acc = 0.f;
    #pragma unroll
    for (int q = 0; q < 4; ++q) {
        int i = i0 + q;
        if (i < m) {
            float r = sv[q + 1] - sv[q];
            rb[i] = r;
            float w = wb[i];
            acc += w * w * r * r;
        }
    }
    float s = blockReduceSum(acc);
    if (threadIdx.x == 0) atomicAdd(&phi[b], s);
}

extern "C" void kernel_launch(void* const* d_in, const int* in_sizes, int n_in,
                              void* d_out, int out_size, void* d_ws, size_t ws_size,
                              hipStream_t stream) {
    const float* u  = (const float*)d_in[0];  // [B, n-1]
    const float* x  = (const float*)d_in[1];  // [B, n]
    const int* idx  = (const int*)d_in[2];    // [K]

    const int B = 16;
    const int n = in_sizes[1] / B;   // 262144
    const int m = n - 1;             // 262143
    const int K = in_sizes[2];       // 131072
    const int NK = B * K;            // 2097152
    const int GRID = NK / CHUNK;     // 512 blocks

    float* out   = (float*)d_out;
    float* phi   = out;                         // [B]
    float* v_out = out + B;                     // [B,K]
    float* r_out = v_out + (size_t)B * K;       // [B,m]
    float* w_out = r_out + (size_t)B * m;       // [B,m]

    char* ws = (char*)d_ws;
    // u64 slots first (8-byte alignment off the 256-aligned ws base)
    unsigned long long* slotA = (unsigned long long*)ws;  ws += sizeof(unsigned long long) * GRID;
    unsigned long long* slotR = (unsigned long long*)ws;  ws += sizeof(unsigned long long) * B * 16;
    float* rg  = (float*)ws;      ws += sizeof(float) * (size_t)NK;   // fallback only
    float* dg  = (float*)ws;      ws += sizeof(float) * (size_t)NK;
    float* cl  = (float*)ws;      ws += sizeof(float) * (size_t)NK;
    float* p0f = (float*)ws;      ws += sizeof(float) * (size_t)NK;
    float* p1f = (float*)ws;      ws += sizeof(float) * (size_t)NK;
    float* kpf = (float*)ws;      ws += sizeof(float) * (size_t)NK;
    float* vf  = (float*)ws;      ws += sizeof(float) * (size_t)NK;
    float* rs_arr  = (float*)ws;  ws += sizeof(float) * (MAX_ITER + 1) * B;
    float* pkp_arr = (float*)ws;  ws += sizeof(float) * MAX_ITER * B;
    float* pbl = (float*)ws;      ws += sizeof(float) * 2 * GRID;
    float* pbr = (float*)ws;      ws += sizeof(float) * 2 * GRID;
    float* rbl = (float*)ws;      ws += sizeof(float) * GRID;
    float* rbr = (float*)ws;      ws += sizeof(float) * GRID;
    int*   pos = (int*)ws;        ws += sizeof(int) * (size_t)n;

    hipMemsetAsync(slotA, 0, sizeof(unsigned long long) * (GRID + B * 16), stream);
    hipMemsetAsync(rs_arr, 0, sizeof(float) * ((MAX_ITER + 1) * B + MAX_ITER * B), stream);
    hipMemsetAsync(pos, 0xFF, sizeof(int) * (size_t)n, stream);  // -1
    hipMemsetAsync(phi, 0, sizeof(float) * B, stream);

    k_scatter<<<(K + 255) / 256, 256, 0, stream>>>(idx, pos, K);

    int tot4w = (B * m) / 4;
    k_w<<<(tot4w + 255) / 256, 256, 0, stream>>>(u, w_out, tot4w);

    int n_ = n, K_ = K, B_ = B, nblk_ = GRID;
    void* args[] = {(void*)&idx, (void*)&w_out, (void*)&x, (void*)&v_out,
                    (void*)&slotA, (void*)&slotR,
                    (void*)&pbl, (void*)&pbr, (void*)&rbl, (void*)&rbr,
                    (void*)&n_, (void*)&K_, (void*)&B_, (void*)&nblk_};
    hipError_t cerr = hipLaunchCooperativeKernel((const void*)k_cg_pers, dim3(GRID),
                                                 dim3(CGBLK), args, 0, stream);
    const float* vsrc = v_out;
    if (cerr != hipSuccess) {
        // fallback: known-good multi-kernel CG loop
        k_init<<<NK / 1024, 256, 0, stream>>>(idx, w_out, x, rg, dg, cl, rs_arr, n, K);
        hipMemsetAsync(vf, 0, sizeof(float) * (size_t)NK, stream);
        for (int it = 0; it < MAX_ITER; ++it) {
            const float* po = (it == 0) ? rg : ((it & 1) ? p0f : p1f);
            float* pnw = (it & 1) ? p1f : p0f;
            k_cg_a<<<NK / 1024, 256, 0, stream>>>(rg, po, pnw, kpf, dg, cl,
                                                  rs_arr, pkp_arr, it, B, K);
            k_cg_b<<<NK / 1024, 256, 0, stream>>>(vf, rg, pnw, kpf,
                                                  rs_arr, pkp_arr, it, B, K);
        }
        hipMemcpyAsync(v_out, vf, sizeof(float) * (size_t)NK, hipMemcpyDeviceToDevice, stream);
        vsrc = vf;
    }

    k_final<<<dim3((m + 1023) / 1024, B), 256, 0, stream>>>(x, w_out, pos, vsrc, r_out, phi, n, K);
}

// Round 8
// 223.822 us; speedup vs baseline: 7.9309x; 7.9309x over previous
//
#include <hip/hip_runtime.h>
#include <math.h>

#define MAX_ITER 20
#define EPS_W 1e-3f
#define CLAMP_MIN 1e-4f
#define CLAMP_MAX 1e4f

#define E 16
#define CGBLK 256
#define CHUNK (E * CGBLK)  // 4096 elements per block; bpb = K/CHUNK = 32

__device__ __forceinline__ float sp_w(float u) {
    float sp = fmaxf(u, 0.f) + log1pf(expf(-fabsf(u)));
    float w = sp + EPS_W;
    return fminf(fmaxf(w, CLAMP_MIN), CLAMP_MAX);
}
__device__ __forceinline__ float nn(float x) { return (x == x) ? x : 0.f; }

// SYSTEM-scope relaxed atomics: cache-bypassing accesses that hit the
// coherence point directly — no stale L1, no buffer_inv storms.
// (Measured r6->r7: poll rounds 21us -> 3.4us with these.)
__device__ __forceinline__ float sys_ldf(const float* p) {
    return __hip_atomic_load(p, __ATOMIC_RELAXED, __HIP_MEMORY_SCOPE_SYSTEM);
}
__device__ __forceinline__ void sys_stf(float* p, float v) {
    __hip_atomic_store(p, v, __ATOMIC_RELAXED, __HIP_MEMORY_SCOPE_SYSTEM);
}
__device__ __forceinline__ unsigned long long sys_ld64(const unsigned long long* p) {
    return __hip_atomic_load(p, __ATOMIC_RELAXED, __HIP_MEMORY_SCOPE_SYSTEM);
}
__device__ __forceinline__ unsigned long long sys_ld64_acq(const unsigned long long* p) {
    return __hip_atomic_load(p, __ATOMIC_ACQUIRE, __HIP_MEMORY_SCOPE_SYSTEM);
}
__device__ __forceinline__ void sys_st64(unsigned long long* p, unsigned long long v) {
    __hip_atomic_store(p, v, __ATOMIC_RELAXED, __HIP_MEMORY_SCOPE_SYSTEM);
}

// result valid on threadIdx.x == 0 only; block must be 256 threads (4 waves)
__device__ __forceinline__ float blockReduceSum(float v) {
    #pragma unroll
    for (int off = 32; off > 0; off >>= 1) v += __shfl_down(v, off, 64);
    __shared__ float smem[4];
    int lane = threadIdx.x & 63, wid = threadIdx.x >> 6;
    if (lane == 0) smem[wid] = v;
    __syncthreads();
    float r = 0.f;
    if (threadIdx.x == 0) r = smem[0] + smem[1] + smem[2] + smem[3];
    return r;
}

// Fused per-batch reduction + barrier. Self-validating {gen|payload} words,
// all system-scope (cache-bypassing). Producer ordering (halo stores before
// arrival publish) is given by the s_waitcnt vmcnt(0) + s_barrier inside
// blockReduceSum's __syncthreads.
__device__ float round_sum(float partial, unsigned gen,
                           unsigned long long* __restrict__ slotA,
                           unsigned long long* __restrict__ slotR,
                           int blk, int bbase, int bpb, int relIdx, bool leader) {
    __shared__ float bsum;
    float bs = blockReduceSum(partial);          // valid on tid 0
    const int tid = threadIdx.x;
    if (tid == 0)
        sys_st64(&slotA[blk], ((unsigned long long)gen << 32) | __float_as_uint(bs));
    if (leader) {
        float lp = 0.f;
        if (tid < bpb) {
            unsigned long long v; int s = 0;
            for (;;) {
                v = sys_ld64(&slotA[bbase + tid]);
                if ((unsigned)(v >> 32) >= gen) break;
                if ((++s & 63) == 0) {           // livelock insurance only
                    v = sys_ld64_acq(&slotA[bbase + tid]);
                    if ((unsigned)(v >> 32) >= gen) break;
                }
                __builtin_amdgcn_s_sleep(1);
            }
            lp = __uint_as_float((unsigned)v);
        }
        #pragma unroll
        for (int off = 16; off > 0; off >>= 1) lp += __shfl_down(lp, off, 32);
        if (tid == 0) {
            sys_st64(&slotR[relIdx], ((unsigned long long)gen << 32) | __float_as_uint(lp));
            bsum = lp;
        }
    } else {
        if (tid == 0) {
            unsigned long long v; int s = 0;
            for (;;) {
                v = sys_ld64(&slotR[relIdx]);
                if ((unsigned)(v >> 32) >= gen) break;
                if ((++s & 63) == 0) {
                    v = sys_ld64_acq(&slotR[relIdx]);
                    if ((unsigned)(v >> 32) >= gen) break;
                }
                __builtin_amdgcn_s_sleep(1);
            }
            bsum = __uint_as_float((unsigned)v);
        }
    }
    __syncthreads();
    return bsum;
}

__global__ __launch_bounds__(256) void k_scatter(const int* __restrict__ idx,
                                                 int* __restrict__ pos, int K) {
    int k = blockIdx.x * 256 + threadIdx.x;
    if (k < K) pos[idx[k]] = k;
}

__global__ __launch_bounds__(256) void k_w(const float* __restrict__ u,
                                           float* __restrict__ w, int total4) {
    int t = blockIdx.x * 256 + threadIdx.x;
    if (t >= total4) return;
    float4 uu = reinterpret_cast<const float4*>(u)[t];
    float4 ww;
    ww.x = sp_w(uu.x); ww.y = sp_w(uu.y); ww.z = sp_w(uu.z); ww.w = sp_w(uu.w);
    reinterpret_cast<float4*>(w)[t] = ww;
}

// Persistent CG, PLAIN launch (graph-capturable; hipLaunchCooperativeKernel
// fails under stream capture). Co-residency by capacity: waves_per_eu(2,2)
// forces 2 blocks/CU; grid = 512 = 2 x 256 CUs, so all blocks resident.
// (Kp)[k] = dg[k]*p[k] - cl[k]*p[k-1] - cl[k+1]*p[k+1]
__global__ __attribute__((amdgpu_flat_work_group_size(256, 256),
                          amdgpu_waves_per_eu(2, 2)))
void k_cg_pers(
        const int* __restrict__ idx, const float* __restrict__ w_all,
        const float* __restrict__ x, float* __restrict__ v_out,
        unsigned long long* __restrict__ slotA,   // [nblk]
        unsigned long long* __restrict__ slotR,   // [B*16], padded per batch
        float* __restrict__ pbl, float* __restrict__ pbr,   // [2*nblk] parity dbuf
        float* __restrict__ rbl, float* __restrict__ rbr,   // [nblk]
        int n, int K, int B, int nblk) {
    const int blk = blockIdx.x, tid = threadIdx.x;
    const int bpb = K / CHUNK;                 // 32 blocks per batch
    const int b = blk / bpb;
    const int bbase = b * bpb;
    const int relIdx = b * 16;
    const bool leader = (blk == bbase);
    const bool first_blk = (blk == bbase);
    const bool last_blk  = (blk == bbase + bpb - 1);
    const int k0 = (blk - bbase) * CHUNK + tid * E;
    const int m = n - 1;
    const float* wb = w_all + (size_t)b * m;
    const float* xb = x + (size_t)b * n;

    // ---------- init: build dg, cl, rhs in registers ----------
    int jj[E + 2];
    #pragma unroll
    for (int t = 0; t < E + 2; ++t) {
        int k = k0 - 1 + t;
        jj[t] = (k >= 0 && k < K) ? idx[k] : -1000000;
    }
    float vv[E], rcg[E], p[E], kp[E], dgr[E], clr[E + 1];
    float s0 = 0.f;
    #pragma unroll
    for (int q = 0; q < E; ++q) {
        int j = jj[q + 1];
        bool la = (jj[q] == j - 1);
        bool ra = (jj[q + 2] == j + 1);
        float wl = 0.f, wr = 0.f;
        if (j >= 1)     { float w = wb[j - 1]; wl = w * w; }
        if (j <= n - 2) { float w = wb[j];     wr = w * w; }
        float rhs = 0.f;
        if (j >= 1 && !la)     rhs += wl * nn(xb[j - 1]);
        if (j <= n - 2 && !ra) rhs += wr * nn(xb[j + 1]);
        vv[q] = 0.f; rcg[q] = rhs; p[q] = rhs; kp[q] = 0.f;
        dgr[q] = wl + wr;
        clr[q] = la ? wl : 0.f;
        s0 += rhs * rhs;
    }
    {   // clr[E] = left coupling of element k0+E (first elem of next thread)
        float cl8 = 0.f;
        int j8 = jj[E + 1];
        if ((k0 + E) < K && jj[E] == j8 - 1) { float w = wb[j8 - 1]; cl8 = w * w; }
        clr[E] = cl8;
    }
    if (tid == 0)         { sys_stf(&rbl[blk], rcg[0]);     sys_stf(&pbl[blk], p[0]); }
    if (tid == CGBLK - 1) { sys_stf(&rbr[blk], rcg[E - 1]); sys_stf(&pbr[blk], p[E - 1]); }

    float rs_prev = 1.f;
    float rs_cur = round_sum(s0, 1u, slotA, slotR, blk, bbase, bpb, relIdx, leader);

    __shared__ float sLa[CGBLK], sRa[CGBLK];

    for (int it = 0; it < MAX_ITER; ++it) {
        // ---- phase A: p update, halos, Kp, p.Kp ----
        float beta = (it > 0) ? rs_cur / (rs_prev + 1e-30f) : 0.f;
        #pragma unroll
        for (int q = 0; q < E; ++q) p[q] = rcg[q] + beta * p[q];
        sLa[tid] = p[0]; sRa[tid] = p[E - 1];
        __syncthreads();
        int rslot = (it & 1) * nblk, wslot = ((it + 1) & 1) * nblk;
        float pl, pr;
        if (tid > 0) pl = sRa[tid - 1];
        else pl = first_blk ? 0.f
                            : (sys_ldf(&rbr[blk - 1]) + beta * sys_ldf(&pbr[rslot + blk - 1]));
        if (tid < CGBLK - 1) pr = sLa[tid + 1];
        else pr = last_blk ? 0.f
                           : (sys_ldf(&rbl[blk + 1]) + beta * sys_ldf(&pbl[rslot + blk + 1]));
        if (tid == 0)         sys_stf(&pbl[wslot + blk], p[0]);
        if (tid == CGBLK - 1) sys_stf(&pbr[wslot + blk], p[E - 1]);
        float dot = 0.f;
        #pragma unroll
        for (int q = 0; q < E; ++q) {
            float pm = (q == 0) ? pl : p[q - 1];
            float pp = (q == E - 1) ? pr : p[q + 1];
            kp[q] = dgr[q] * p[q] - clr[q] * pm - clr[q + 1] * pp;
            dot += p[q] * kp[q];
        }
        float pkp = round_sum(dot, 2u + 2u * it, slotA, slotR, blk, bbase, bpb, relIdx, leader);

        // ---- phase B: alpha, v/rcg update, ||r||^2 ----
        float alpha = rs_cur / (pkp + 1e-30f);
        float dot2 = 0.f;
        #pragma unroll
        for (int q = 0; q < E; ++q) {
            vv[q] += alpha * p[q];
            rcg[q] -= alpha * kp[q];
            dot2 += rcg[q] * rcg[q];
        }
        if (tid == 0)         sys_stf(&rbl[blk], rcg[0]);
        if (tid == CGBLK - 1) sys_stf(&rbr[blk], rcg[E - 1]);
        float rs_new = round_sum(dot2, 3u + 2u * it, slotA, slotR, blk, bbase, bpb, relIdx, leader);
        rs_prev = rs_cur; rs_cur = rs_new;
    }

    float* vb = v_out + (size_t)b * K + (size_t)(blk - bbase) * CHUNK + (size_t)tid * E;
    #pragma unroll
    for (int q4 = 0; q4 < E / 4; ++q4)
        reinterpret_cast<float4*>(vb)[q4] =
            make_float4(vv[4 * q4], vv[4 * q4 + 1], vv[4 * q4 + 2], vv[4 * q4 + 3]);
}

// final: r = D(x_known + scatter(v)), phi = sum w^2 r^2
__global__ __launch_bounds__(256) void k_final(const float* __restrict__ x,
                                               const float* __restrict__ w_out,
                                               const int* __restrict__ pos,
                                               const float* __restrict__ v,
                                               float* __restrict__ r_out,
                                               float* __restrict__ phi,
                                               int n, int K) {
    int m = n - 1;
    int b = blockIdx.y;
    int i0 = (blockIdx.x * 256 + threadIdx.x) * 4;
    const float* xb = x + (size_t)b * n;
    const float* wb = w_out + (size_t)b * m;
    const float* vb = v + (size_t)b * K;
    float* rb = r_out + (size_t)b * m;
    float sv[5];
    #pragma unroll
    for (int q = 0; q < 5; ++q) {
        int i = i0 + q;
        if (i <= m) {
            int p = pos[i];
            sv[q] = (p >= 0) ? vb[p] : nn(xb[i]);
        } else sv[q] = 0.f;
    }
    float acc = 0.f;
    #pragma unroll
    for (int q = 0; q < 4; ++q) {
        int i = i0 + q;
        if (i < m) {
            float r = sv[q + 1] - sv[q];
            rb[i] = r;
            float w = wb[i];
            acc += w * w * r * r;
        }
    }
    float s = blockReduceSum(acc);
    if (threadIdx.x == 0) atomicAdd(&phi[b], s);
}

extern "C" void kernel_launch(void* const* d_in, const int* in_sizes, int n_in,
                              void* d_out, int out_size, void* d_ws, size_t ws_size,
                              hipStream_t stream) {
    const float* u  = (const float*)d_in[0];  // [B, n-1]
    const float* x  = (const float*)d_in[1];  // [B, n]
    const int* idx  = (const int*)d_in[2];    // [K]

    const int B = 16;
    const int n = in_sizes[1] / B;   // 262144
    const int m = n - 1;             // 262143
    const int K = in_sizes[2];       // 131072
    const int NK = B * K;            // 2097152
    const int GRID = NK / CHUNK;     // 512 blocks = 2 per CU

    float* out   = (float*)d_out;
    float* phi   = out;                         // [B]
    float* v_out = out + B;                     // [B,K]
    float* r_out = v_out + (size_t)B * K;       // [B,m]
    float* w_out = r_out + (size_t)B * m;       // [B,m]

    char* ws = (char*)d_ws;
    // u64 slots first (8-byte alignment off the aligned ws base)
    unsigned long long* slotA = (unsigned long long*)ws;  ws += sizeof(unsigned long long) * GRID;
    unsigned long long* slotR = (unsigned long long*)ws;  ws += sizeof(unsigned long long) * B * 16;
    float* pbl = (float*)ws;      ws += sizeof(float) * 2 * GRID;
    float* pbr = (float*)ws;      ws += sizeof(float) * 2 * GRID;
    float* rbl = (float*)ws;      ws += sizeof(float) * GRID;
    float* rbr = (float*)ws;      ws += sizeof(float) * GRID;
    int*   pos = (int*)ws;        ws += sizeof(int) * (size_t)n;

    hipMemsetAsync(slotA, 0, sizeof(unsigned long long) * (GRID + B * 16), stream);
    hipMemsetAsync(pos, 0xFF, sizeof(int) * (size_t)n, stream);  // -1
    hipMemsetAsync(phi, 0, sizeof(float) * B, stream);

    k_scatter<<<(K + 255) / 256, 256, 0, stream>>>(idx, pos, K);

    int tot4w = (B * m) / 4;
    k_w<<<(tot4w + 255) / 256, 256, 0, stream>>>(u, w_out, tot4w);

    k_cg_pers<<<GRID, CGBLK, 0, stream>>>(idx, w_out, x, v_out,
                                          slotA, slotR, pbl, pbr, rbl, rbr,
                                          n, K, B, GRID);

    k_final<<<dim3((m + 1023) / 1024, B), 256, 0, stream>>>(x, w_out, pos, v_out, r_out, phi, n, K);
}

// Round 9
// 180.923 us; speedup vs baseline: 9.8113x; 1.2371x over previous
//
#include <hip/hip_runtime.h>
#include <math.h>

#define MAX_ITER 20
#define EPS_W 1e-3f
#define CLAMP_MIN 1e-4f
#define CLAMP_MAX 1e4f

#define E 16
#define CGBLK 256
#define CHUNK (E * CGBLK)  // 4096 elems/block; bpb = K/CHUNK = 32

__device__ __forceinline__ float sp_w(float u) {
    float sp = fmaxf(u, 0.f) + log1pf(expf(-fabsf(u)));
    float w = sp + EPS_W;
    return fminf(fmaxf(w, CLAMP_MIN), CLAMP_MAX);
}
__device__ __forceinline__ float nn(float x) { return (x == x) ? x : 0.f; }

// SYSTEM-scope relaxed atomics: cache-bypassing, coherence-point direct.
// (Measured r6->r7: poll rounds 21us -> 3.4us.)
__device__ __forceinline__ unsigned long long sys_ld64(const unsigned long long* p) {
    return __hip_atomic_load(p, __ATOMIC_RELAXED, __HIP_MEMORY_SCOPE_SYSTEM);
}
__device__ __forceinline__ unsigned long long sys_ld64_acq(const unsigned long long* p) {
    return __hip_atomic_load(p, __ATOMIC_ACQUIRE, __HIP_MEMORY_SCOPE_SYSTEM);
}
__device__ __forceinline__ void sys_st64(unsigned long long* p, unsigned long long v) {
    __hip_atomic_store(p, v, __ATOMIC_RELAXED, __HIP_MEMORY_SCOPE_SYSTEM);
}
// Poll a {gen|payload} word until tag >= gen. Self-validating: value and tag
// come from the same 64-bit read, so no fences needed.
__device__ __forceinline__ unsigned long long poll_tag(const unsigned long long* p, unsigned gen) {
    unsigned long long v; int s = 0;
    for (;;) {
        v = sys_ld64(p);
        if ((unsigned)(v >> 32) >= gen) return v;
        if ((++s & 63) == 0) {               // livelock insurance only
            v = sys_ld64_acq(p);
            if ((unsigned)(v >> 32) >= gen) return v;
        }
        __builtin_amdgcn_s_sleep(1);
    }
}
__device__ __forceinline__ unsigned long long mkword(unsigned gen, float f) {
    return ((unsigned long long)gen << 32) | (unsigned long long)__float_as_uint(f);
}

// valid on tid 0 only; block = 256 threads (4 waves)
__device__ __forceinline__ float blockReduceSum(float v) {
    #pragma unroll
    for (int off = 32; off > 0; off >>= 1) v += __shfl_down(v, off, 64);
    __shared__ float smem[4];
    int lane = threadIdx.x & 63, wid = threadIdx.x >> 6;
    if (lane == 0) smem[wid] = v;
    __syncthreads();
    float r = 0.f;
    if (threadIdx.x == 0) r = smem[0] + smem[1] + smem[2] + smem[3];
    return r;
}
// paired reduction; valid on tid 0 only
__device__ __forceinline__ float2 blockReduceSum2(float a, float b) {
    #pragma unroll
    for (int off = 32; off > 0; off >>= 1) {
        a += __shfl_down(a, off, 64);
        b += __shfl_down(b, off, 64);
    }
    __shared__ float sa[4], sb[4];
    int lane = threadIdx.x & 63, wid = threadIdx.x >> 6;
    if (lane == 0) { sa[wid] = a; sb[wid] = b; }
    __syncthreads();
    float ra = 0.f, rb = 0.f;
    if (threadIdx.x == 0) {
        ra = sa[0] + sa[1] + sa[2] + sa[3];
        rb = sb[0] + sb[1] + sb[2] + sb[3];
    }
    return make_float2(ra, rb);
}

// fused: w = clip(softplus(u)+eps) elementwise (float4) + pos scatter
__global__ __launch_bounds__(256) void k_pre(const float* __restrict__ u,
                                             float* __restrict__ w,
                                             const int* __restrict__ idx,
                                             int* __restrict__ pos,
                                             int total4, int K) {
    int t = blockIdx.x * 256 + threadIdx.x;
    if (t < total4) {
        float4 uu = reinterpret_cast<const float4*>(u)[t];
        float4 ww;
        ww.x = sp_w(uu.x); ww.y = sp_w(uu.y); ww.z = sp_w(uu.z); ww.w = sp_w(uu.w);
        reinterpret_cast<float4*>(w)[t] = ww;
    }
    if (t < K) pos[idx[t]] = t;
}

// Persistent single-reduction CG. Plain launch (graph-capturable); co-residency
// by capacity: waves_per_eu(2,2) -> 2 blocks/CU, grid 512 = 2 x 256 CU
// (empirically proven r5-r8: spin barriers completed => all blocks resident).
// One fused all-to-all round per iteration:
//   d1 = p.Kp, d2 = Kp.Kp reduced together; alpha = rs/d1;
//   rs' = alpha^2*d2 - rs  (exact via (r,Kp)=(p,Kp) conjugacy; >=0 by C-S).
// Neighbor edges mirrored bitwise in tid0/tid255 registers; only Kp edges are
// exchanged per round (gen-tagged, parity double-buffered).
__global__ __attribute__((amdgpu_flat_work_group_size(256, 256),
                          amdgpu_waves_per_eu(2, 2)))
void k_cg_pers(const int* __restrict__ idx, const float* __restrict__ w_all,
               const float* __restrict__ x, float* __restrict__ v_out,
               unsigned long long* __restrict__ slotD,  // [2][nblk][4]
               unsigned long long* __restrict__ slotK,  // [2][2][nblk]
               int n, int K, int B, int nblk) {
    const int blk = blockIdx.x, tid = threadIdx.x;
    const int bpb = K / CHUNK;                  // 32
    const int b = blk / bpb, bbase = b * bpb;
    const bool first = (blk == bbase), last = (blk == bbase + bpb - 1);
    const int k0 = (blk - bbase) * CHUNK + tid * E;
    const int m = n - 1;
    const float* wb = w_all + (size_t)b * m;
    const float* xb = x + (size_t)b * n;

    // ---- init: dg, cl, r0 in registers ----
    int jj[E + 2];
    #pragma unroll
    for (int t = 0; t < E + 2; ++t) {
        int k = k0 - 1 + t;
        jj[t] = (k >= 0 && k < K) ? idx[k] : -1000000;
    }
    float vv[E], r[E], p[E], kp[E], dgr[E], clr[E + 1];
    float s0 = 0.f;
    #pragma unroll
    for (int q = 0; q < E; ++q) {
        int j = jj[q + 1];
        bool la = (jj[q] == j - 1);
        bool ra = (jj[q + 2] == j + 1);
        float wl = 0.f, wr = 0.f;
        if (j >= 1)     { float w = wb[j - 1]; wl = w * w; }
        if (j <= n - 2) { float w = wb[j];     wr = w * w; }
        float rhs = 0.f;
        if (j >= 1 && !la)     rhs += wl * nn(xb[j - 1]);
        if (j <= n - 2 && !ra) rhs += wr * nn(xb[j + 1]);
        vv[q] = 0.f; r[q] = rhs; p[q] = 0.f; kp[q] = 0.f;
        dgr[q] = wl + wr;
        clr[q] = la ? wl : 0.f;
        s0 += rhs * rhs;
    }
    {
        float cl8 = 0.f;
        int j8 = jj[E + 1];
        if ((k0 + E) < K && jj[E] == j8 - 1) { float w = wb[j8 - 1]; cl8 = w * w; }
        clr[E] = cl8;
    }
    // publish initial r-edges (tag 1, parity-1 K slots)
    if (tid == 0)
        sys_st64(&slotK[1 * 2 * nblk + 0 * nblk + blk], mkword(1u, r[0]));
    if (tid == CGBLK - 1)
        sys_st64(&slotK[1 * 2 * nblk + 1 * nblk + blk], mkword(1u, r[E - 1]));

    float s0b = blockReduceSum(s0);   // tid0; published with round 0

    __shared__ float sLa[CGBLK], sRa[CGBLK];
    __shared__ float sm[3];           // D1, D2, RS0

    float rs = 0.f, beta = 0.f;
    float r_nbL = 0.f, p_nbL = 0.f;   // live in tid 0
    float r_nbR = 0.f, p_nbR = 0.f;   // live in tid 255

    for (int it = 0; it < MAX_ITER; ++it) {
        const unsigned G = (unsigned)(it + 2);
        const int par = it & 1;
        if (it == 0) {   // fetch neighbor r0 edges (self-tagged; no barrier needed)
            if (tid == 0 && !first) {
                unsigned long long v0 = poll_tag(&slotK[1 * 2 * nblk + 1 * nblk + (blk - 1)], 1u);
                r_nbL = __uint_as_float((unsigned)v0);
            }
            if (tid == CGBLK - 1 && !last) {
                unsigned long long v0 = poll_tag(&slotK[1 * 2 * nblk + 0 * nblk + (blk + 1)], 1u);
                r_nbR = __uint_as_float((unsigned)v0);
            }
        }
        // p update (beta=0 at it=0) + bitwise neighbor mirror
        #pragma unroll
        for (int q = 0; q < E; ++q) p[q] = r[q] + beta * p[q];
        if (tid == 0)         p_nbL = r_nbL + beta * p_nbL;
        if (tid == CGBLK - 1) p_nbR = r_nbR + beta * p_nbR;
        sLa[tid] = p[0]; sRa[tid] = p[E - 1];
        __syncthreads();
        float pl = (tid > 0) ? sRa[tid - 1] : (first ? 0.f : p_nbL);
        float pr = (tid < CGBLK - 1) ? sLa[tid + 1] : (last ? 0.f : p_nbR);
        float d1 = 0.f, d2 = 0.f;
        #pragma unroll
        for (int q = 0; q < E; ++q) {
            float pm = (q == 0) ? pl : p[q - 1];
            float pp = (q == E - 1) ? pr : p[q + 1];
            kp[q] = dgr[q] * p[q] - clr[q] * pm - clr[q + 1] * pp;
            d1 += p[q] * kp[q];
            d2 += kp[q] * kp[q];
        }
        // publish Kp edges early (gen-tagged, parity-buffered)
        if (tid == 0)
            sys_st64(&slotK[par * 2 * nblk + 0 * nblk + blk], mkword(G, kp[0]));
        if (tid == CGBLK - 1)
            sys_st64(&slotK[par * 2 * nblk + 1 * nblk + blk], mkword(G, kp[E - 1]));
        float2 db = blockReduceSum2(d1, d2);
        if (tid == 0) {
            unsigned long long* base = &slotD[((size_t)par * nblk + blk) * 4];
            sys_st64(base + 0, mkword(G, db.x));
            sys_st64(base + 1, mkword(G, db.y));
            if (it == 0) sys_st64(base + 2, mkword(G, s0b));
        }
        // ---- all-to-all poll: one fabric hop ----
        float kpnbl = 0.f, kpnbr = 0.f;
        {
            int lane = tid & 63, wid = tid >> 6;
            if (wid == 0) {
                int which = lane >> 5;              // 0:d1  1:d2
                int li = lane & 31;
                float pv = 0.f;
                if (li < bpb) {
                    unsigned long long v0 =
                        poll_tag(&slotD[((size_t)par * nblk + (bbase + li)) * 4 + which], G);
                    pv = __uint_as_float((unsigned)v0);
                }
                #pragma unroll
                for (int off = 16; off > 0; off >>= 1) pv += __shfl_down(pv, off, 32);
                if (lane == 0)  sm[0] = pv;
                if (lane == 32) sm[1] = pv;
            } else if (wid == 1 && it == 0 && lane < 32) {
                float pv = 0.f;
                if (lane < bpb) {
                    unsigned long long v0 =
                        poll_tag(&slotD[((size_t)0 * nblk + (bbase + lane)) * 4 + 2], 2u);
                    pv = __uint_as_float((unsigned)v0);
                }
                #pragma unroll
                for (int off = 16; off > 0; off >>= 1) pv += __shfl_down(pv, off, 32);
                if (lane == 0) sm[2] = pv;
            }
            if (tid == 0 && !first) {
                unsigned long long v0 = poll_tag(&slotK[par * 2 * nblk + 1 * nblk + (blk - 1)], G);
                kpnbl = __uint_as_float((unsigned)v0);
            }
            if (tid == CGBLK - 1 && !last) {
                unsigned long long v0 = poll_tag(&slotK[par * 2 * nblk + 0 * nblk + (blk + 1)], G);
                kpnbr = __uint_as_float((unsigned)v0);
            }
        }
        __syncthreads();
        float D1 = sm[0], D2 = sm[1];
        if (it == 0) rs = sm[2];
        float alpha = rs / (D1 + 1e-30f);
        float rs_new = fmaxf(alpha * alpha * D2 - rs, 0.f);
        #pragma unroll
        for (int q = 0; q < E; ++q) {
            vv[q] += alpha * p[q];
            r[q]  -= alpha * kp[q];
        }
        if (tid == 0 && !first)        r_nbL -= alpha * kpnbl;
        if (tid == CGBLK - 1 && !last) r_nbR -= alpha * kpnbr;
        beta = rs_new / (rs + 1e-30f);
        rs = rs_new;
    }

    float* vb = v_out + (size_t)b * K + (size_t)(blk - bbase) * CHUNK + (size_t)tid * E;
    #pragma unroll
    for (int q4 = 0; q4 < E / 4; ++q4)
        reinterpret_cast<float4*>(vb)[q4] =
            make_float4(vv[4 * q4], vv[4 * q4 + 1], vv[4 * q4 + 2], vv[4 * q4 + 3]);
}

// final: r = D(x_known + scatter(v)), phi = sum w^2 r^2
__global__ __launch_bounds__(256) void k_final(const float* __restrict__ x,
                                               const float* __restrict__ w_out,
                                               const int* __restrict__ pos,
                                               const float* __restrict__ v,
                                               float* __restrict__ r_out,
                                               float* __restrict__ phi,
                                               int n, int K) {
    int m = n - 1;
    int b = blockIdx.y;
    int i0 = (blockIdx.x * 256 + threadIdx.x) * 4;
    const float* xb = x + (size_t)b * n;
    const float* wb = w_out + (size_t)b * m;
    const float* vb = v + (size_t)b * K;
    float* rb = r_out + (size_t)b * m;
    float sv[5];
    #pragma unroll
    for (int q = 0; q < 5; ++q) {
        int i = i0 + q;
        if (i <= m) {
            int p = pos[i];
            sv[q] = (p >= 0) ? vb[p] : nn(xb[i]);
        } else sv[q] = 0.f;
    }
    float acc = 0.f;
    #pragma unroll
    for (int q = 0; q < 4; ++q) {
        int i = i0 + q;
        if (i < m) {
            float r = sv[q + 1] - sv[q];
            rb[i] = r;
            float w = wb[i];
            acc += w * w * r * r;
        }
    }
    float s = blockReduceSum(acc);
    if (threadIdx.x == 0) atomicAdd(&phi[b], s);
}

extern "C" void kernel_launch(void* const* d_in, const int* in_sizes, int n_in,
                              void* d_out, int out_size, void* d_ws, size_t ws_size,
                              hipStream_t stream) {
    const float* u  = (const float*)d_in[0];  // [B, n-1]
    const float* x  = (const float*)d_in[1];  // [B, n]
    const int* idx  = (const int*)d_in[2];    // [K]

    const int B = 16;
    const int n = in_sizes[1] / B;   // 262144
    const int m = n - 1;             // 262143
    const int K = in_sizes[2];       // 131072
    const int NK = B * K;            // 2097152
    const int GRID = NK / CHUNK;     // 512 blocks = 2 per CU

    float* out   = (float*)d_out;
    float* phi   = out;                         // [B]
    float* v_out = out + B;                     // [B,K]
    float* r_out = v_out + (size_t)B * K;       // [B,m]
    float* w_out = r_out + (size_t)B * m;       // [B,m]

    char* ws = (char*)d_ws;
    unsigned long long* slotD = (unsigned long long*)ws;  ws += sizeof(unsigned long long) * 2 * GRID * 4;
    unsigned long long* slotK = (unsigned long long*)ws;  ws += sizeof(unsigned long long) * 2 * 2 * GRID;
    int* pos = (int*)ws;                                  ws += sizeof(int) * (size_t)n;

    hipMemsetAsync(slotD, 0, sizeof(unsigned long long) * (2 * GRID * 4 + 2 * 2 * GRID), stream);
    hipMemsetAsync(pos, 0xFF, sizeof(int) * (size_t)n, stream);  // -1
    hipMemsetAsync(phi, 0, sizeof(float) * B, stream);

    int tot4w = (B * m) / 4;
    k_pre<<<(tot4w + 255) / 256, 256, 0, stream>>>(u, w_out, idx, pos, tot4w, K);

    k_cg_pers<<<GRID, CGBLK, 0, stream>>>(idx, w_out, x, v_out,
                                          slotD, slotK, n, K, B, GRID);

    k_final<<<dim3((m + 1023) / 1024, B), 256, 0, stream>>>(x, w_out, pos, v_out, r_out, phi, n, K);
}

// Round 10
// 168.047 us; speedup vs baseline: 10.5631x; 1.0766x over previous
//
#include <hip/hip_runtime.h>
#include <math.h>

#define MAX_ITER 20
#define EPS_W 1e-3f
#define CLAMP_MIN 1e-4f
#define CLAMP_MAX 1e4f

#define E 16
#define CGBLK 256
#define CHUNK (E * CGBLK)  // 4096 elems/block; bpb = K/CHUNK = 32

__device__ __forceinline__ float sp_w(float u) {
    float sp = fmaxf(u, 0.f) + log1pf(expf(-fabsf(u)));
    float w = sp + EPS_W;
    return fminf(fmaxf(w, CLAMP_MIN), CLAMP_MAX);
}
__device__ __forceinline__ float nn(float x) { return (x == x) ? x : 0.f; }

// SYSTEM-scope relaxed atomics: cache-bypassing, coherence-point direct.
// (Measured r6->r7: poll rounds 21us -> 3.4us.)
__device__ __forceinline__ unsigned long long sys_ld64(const unsigned long long* p) {
    return __hip_atomic_load(p, __ATOMIC_RELAXED, __HIP_MEMORY_SCOPE_SYSTEM);
}
__device__ __forceinline__ unsigned long long sys_ld64_acq(const unsigned long long* p) {
    return __hip_atomic_load(p, __ATOMIC_ACQUIRE, __HIP_MEMORY_SCOPE_SYSTEM);
}
__device__ __forceinline__ void sys_st64(unsigned long long* p, unsigned long long v) {
    __hip_atomic_store(p, v, __ATOMIC_RELAXED, __HIP_MEMORY_SCOPE_SYSTEM);
}
__device__ __forceinline__ unsigned long long poll_tag(const unsigned long long* p, unsigned gen) {
    unsigned long long v; int s = 0;
    for (;;) {
        v = sys_ld64(p);
        if ((unsigned)(v >> 32) >= gen) return v;
        if ((++s & 63) == 0) {               // livelock insurance only
            v = sys_ld64_acq(p);
            if ((unsigned)(v >> 32) >= gen) return v;
        }
        __builtin_amdgcn_s_sleep(1);
    }
}
__device__ __forceinline__ unsigned long long mkword(unsigned gen, float f) {
    return ((unsigned long long)gen << 32) | (unsigned long long)__float_as_uint(f);
}

// valid on tid 0 only; block = 256 threads (4 waves)
__device__ __forceinline__ float blockReduceSum(float v) {
    #pragma unroll
    for (int off = 32; off > 0; off >>= 1) v += __shfl_down(v, off, 64);
    __shared__ float smem[4];
    int lane = threadIdx.x & 63, wid = threadIdx.x >> 6;
    if (lane == 0) smem[wid] = v;
    __syncthreads();
    float r = 0.f;
    if (threadIdx.x == 0) r = smem[0] + smem[1] + smem[2] + smem[3];
    return r;
}
// paired reduction; valid on tid 0 only
__device__ __forceinline__ float2 blockReduceSum2(float a, float b) {
    #pragma unroll
    for (int off = 32; off > 0; off >>= 1) {
        a += __shfl_down(a, off, 64);
        b += __shfl_down(b, off, 64);
    }
    __shared__ float sa[4], sb[4];
    int lane = threadIdx.x & 63, wid = threadIdx.x >> 6;
    if (lane == 0) { sa[wid] = a; sb[wid] = b; }
    __syncthreads();
    float ra = 0.f, rb = 0.f;
    if (threadIdx.x == 0) {
        ra = sa[0] + sa[1] + sa[2] + sa[3];
        rb = sb[0] + sb[1] + sb[2] + sb[3];
    }
    return make_float2(ra, rb);
}

// pos scatter only (pos pre-filled to -1 by memset)
__global__ __launch_bounds__(256) void k_scatter(const int* __restrict__ idx,
                                                 int* __restrict__ pos, int K) {
    int k = blockIdx.x * 256 + threadIdx.x;
    if (k < K) pos[idx[k]] = k;
}

// Persistent single-reduction CG. Plain launch (graph-capturable); co-residency
// by capacity: waves_per_eu(2,2) -> 2 blocks/CU, grid 512 = 2 x 256 CU
// (empirically proven r5-r9: spin rounds complete => all blocks resident).
// Reads u directly (w = sp_w(u) computed on the fly; VALU is ~87% idle).
__global__ __attribute__((amdgpu_flat_work_group_size(256, 256),
                          amdgpu_waves_per_eu(2, 2)))
void k_cg_pers(const int* __restrict__ idx, const float* __restrict__ u_all,
               const float* __restrict__ x, float* __restrict__ v_out,
               float* __restrict__ phi,
               unsigned long long* __restrict__ slotD,  // [2][nblk][4]
               unsigned long long* __restrict__ slotK,  // [2][2][nblk]
               int n, int K, int B, int nblk) {
    const int blk = blockIdx.x, tid = threadIdx.x;
    const int bpb = K / CHUNK;                  // 32
    const int b = blk / bpb, bbase = b * bpb;
    const bool first = (blk == bbase), last = (blk == bbase + bpb - 1);
    const int k0 = (blk - bbase) * CHUNK + tid * E;
    const int m = n - 1;
    const float* ub = u_all + (size_t)b * m;
    const float* xb = x + (size_t)b * n;

    if (blk == 0 && tid < B) phi[tid] = 0.f;   // replay-idempotent phi reset

    // ---- init: dg, cl, r0 in registers ----
    int jj[E + 2];
    {
        const int4* ip = reinterpret_cast<const int4*>(idx + k0);  // k0 % 16 == 0
        #pragma unroll
        for (int q4 = 0; q4 < E / 4; ++q4) {
            int4 t = ip[q4];
            jj[1 + 4 * q4] = t.x; jj[2 + 4 * q4] = t.y;
            jj[3 + 4 * q4] = t.z; jj[4 + 4 * q4] = t.w;
        }
        jj[0]     = (k0 > 0)      ? idx[k0 - 1] : -1000000;
        jj[E + 1] = (k0 + E < K)  ? idx[k0 + E] : -1000000;
    }
    float vv[E], r[E], p[E], kp[E], dgr[E], clr[E + 1];
    float s0 = 0.f;
    float prev_wr = 0.f;
    #pragma unroll
    for (int q = 0; q < E; ++q) {
        int j = jj[q + 1];
        bool la = (jj[q] == j - 1);
        bool ra = (jj[q + 2] == j + 1);
        float wl = 0.f, wr = 0.f;
        if (j >= 1) {
            if (q > 0 && la) wl = prev_wr;                 // share neighbor's w^2
            else { float w = sp_w(ub[j - 1]); wl = w * w; }
        }
        if (j <= n - 2) { float w = sp_w(ub[j]); wr = w * w; }
        prev_wr = wr;
        float rhs = 0.f;
        if (j >= 1 && !la)     rhs += wl * nn(xb[j - 1]);
        if (j <= n - 2 && !ra) rhs += wr * nn(xb[j + 1]);
        vv[q] = 0.f; r[q] = rhs; p[q] = 0.f; kp[q] = 0.f;
        dgr[q] = wl + wr;
        clr[q] = la ? wl : 0.f;
        s0 += rhs * rhs;
    }
    {
        float cl8 = 0.f;
        int j8 = jj[E + 1];
        if ((k0 + E) < K && jj[E] == j8 - 1) { float w = sp_w(ub[j8 - 1]); cl8 = w * w; }
        clr[E] = cl8;
    }
    // publish initial r-edges (tag 1, parity-1 K slots)
    if (tid == 0)
        sys_st64(&slotK[1 * 2 * nblk + 0 * nblk + blk], mkword(1u, r[0]));
    if (tid == CGBLK - 1)
        sys_st64(&slotK[1 * 2 * nblk + 1 * nblk + blk], mkword(1u, r[E - 1]));

    float s0b = blockReduceSum(s0);   // tid0; published with round 0

    __shared__ float sLa[CGBLK], sRa[CGBLK];
    __shared__ float sm[3];           // D1, D2, RS0

    float rs = 0.f, beta = 0.f;
    float r_nbL = 0.f, p_nbL = 0.f;   // live in tid 0
    float r_nbR = 0.f, p_nbR = 0.f;   // live in tid 255

    for (int it = 0; it < MAX_ITER; ++it) {
        const unsigned G = (unsigned)(it + 2);
        const int par = it & 1;
        if (it == 0) {   // fetch neighbor r0 edges (self-tagged)
            if (tid == 0 && !first) {
                unsigned long long v0 = poll_tag(&slotK[1 * 2 * nblk + 1 * nblk + (blk - 1)], 1u);
                r_nbL = __uint_as_float((unsigned)v0);
            }
            if (tid == CGBLK - 1 && !last) {
                unsigned long long v0 = poll_tag(&slotK[1 * 2 * nblk + 0 * nblk + (blk + 1)], 1u);
                r_nbR = __uint_as_float((unsigned)v0);
            }
        }
        // p update (beta=0 at it=0) + bitwise neighbor mirror
        #pragma unroll
        for (int q = 0; q < E; ++q) p[q] = r[q] + beta * p[q];
        if (tid == 0)         p_nbL = r_nbL + beta * p_nbL;
        if (tid == CGBLK - 1) p_nbR = r_nbR + beta * p_nbR;
        sLa[tid] = p[0]; sRa[tid] = p[E - 1];
        __syncthreads();
        float pl = (tid > 0) ? sRa[tid - 1] : (first ? 0.f : p_nbL);
        float pr = (tid < CGBLK - 1) ? sLa[tid + 1] : (last ? 0.f : p_nbR);
        float d1 = 0.f, d2 = 0.f;
        #pragma unroll
        for (int q = 0; q < E; ++q) {
            float pm = (q == 0) ? pl : p[q - 1];
            float pp = (q == E - 1) ? pr : p[q + 1];
            kp[q] = dgr[q] * p[q] - clr[q] * pm - clr[q + 1] * pp;
            d1 += p[q] * kp[q];
            d2 += kp[q] * kp[q];
        }
        // publish Kp edges early (gen-tagged, parity-buffered)
        if (tid == 0)
            sys_st64(&slotK[par * 2 * nblk + 0 * nblk + blk], mkword(G, kp[0]));
        if (tid == CGBLK - 1)
            sys_st64(&slotK[par * 2 * nblk + 1 * nblk + blk], mkword(G, kp[E - 1]));
        float2 db = blockReduceSum2(d1, d2);
        if (tid == 0) {
            unsigned long long* base = &slotD[((size_t)par * nblk + blk) * 4];
            sys_st64(base + 0, mkword(G, db.x));
            sys_st64(base + 1, mkword(G, db.y));
            if (it == 0) sys_st64(base + 2, mkword(G, s0b));
        }
        // ---- all-to-all poll: one fabric hop ----
        float kpnbl = 0.f, kpnbr = 0.f;
        {
            int lane = tid & 63, wid = tid >> 6;
            if (wid == 0) {
                int which = lane >> 5;              // 0:d1  1:d2
                int li = lane & 31;
                float pv = 0.f;
                if (li < bpb) {
                    unsigned long long v0 =
                        poll_tag(&slotD[((size_t)par * nblk + (bbase + li)) * 4 + which], G);
                    pv = __uint_as_float((unsigned)v0);
                }
                #pragma unroll
                for (int off = 16; off > 0; off >>= 1) pv += __shfl_down(pv, off, 32);
                if (lane == 0)  sm[0] = pv;
                if (lane == 32) sm[1] = pv;
            } else if (wid == 1 && it == 0 && lane < 32) {
                float pv = 0.f;
                if (lane < bpb) {
                    unsigned long long v0 =
                        poll_tag(&slotD[((size_t)0 * nblk + (bbase + lane)) * 4 + 2], 2u);
                    pv = __uint_as_float((unsigned)v0);
                }
                #pragma unroll
                for (int off = 16; off > 0; off >>= 1) pv += __shfl_down(pv, off, 32);
                if (lane == 0) sm[2] = pv;
            }
            if (tid == 0 && !first) {
                unsigned long long v0 = poll_tag(&slotK[par * 2 * nblk + 1 * nblk + (blk - 1)], G);
                kpnbl = __uint_as_float((unsigned)v0);
            }
            if (tid == CGBLK - 1 && !last) {
                unsigned long long v0 = poll_tag(&slotK[par * 2 * nblk + 0 * nblk + (blk + 1)], G);
                kpnbr = __uint_as_float((unsigned)v0);
            }
        }
        __syncthreads();
        float D1 = sm[0], D2 = sm[1];
        if (it == 0) rs = sm[2];
        float alpha = rs / (D1 + 1e-30f);
        float rs_new = fmaxf(alpha * alpha * D2 - rs, 0.f);
        #pragma unroll
        for (int q = 0; q < E; ++q) {
            vv[q] += alpha * p[q];
            r[q]  -= alpha * kp[q];
        }
        if (tid == 0 && !first)        r_nbL -= alpha * kpnbl;
        if (tid == CGBLK - 1 && !last) r_nbR -= alpha * kpnbr;
        beta = rs_new / (rs + 1e-30f);
        rs = rs_new;
    }

    float* vb = v_out + (size_t)b * K + (size_t)(blk - bbase) * CHUNK + (size_t)tid * E;
    #pragma unroll
    for (int q4 = 0; q4 < E / 4; ++q4)
        reinterpret_cast<float4*>(vb)[q4] =
            make_float4(vv[4 * q4], vv[4 * q4 + 1], vv[4 * q4 + 2], vv[4 * q4 + 3]);
}

// final, vectorized: w = sp_w(u) computed here (writes w_out),
// r = D(x_known + scatter(v)), phi = sum w^2 r^2
__global__ __launch_bounds__(256) void k_final(const float* __restrict__ u,
                                               const float* __restrict__ x,
                                               const int* __restrict__ pos,
                                               const float* __restrict__ v,
                                               float* __restrict__ w_out,
                                               float* __restrict__ r_out,
                                               float* __restrict__ phi,
                                               int n, int K) {
    int m = n - 1;
    int b = blockIdx.y;
    int i0 = (blockIdx.x * 256 + threadIdx.x) * 4;   // i0+3 <= n-1 by grid sizing
    const float* xb = x + (size_t)b * n;
    const float* ub = u + (size_t)b * m;
    const float* vb = v + (size_t)b * K;
    float* wb = w_out + (size_t)b * m;
    float* rb = r_out + (size_t)b * m;

    int4 pp = *reinterpret_cast<const int4*>(pos + i0);
    int p5 = (i0 + 4 < n) ? pos[i0 + 4] : -1;
    float4 xx = *reinterpret_cast<const float4*>(xb + i0);
    float x5 = (i0 + 4 < n) ? xb[i0 + 4] : 0.f;
    float uu[4];
    if (i0 + 4 <= m) {
        float4 t = *reinterpret_cast<const float4*>(ub + i0);
        uu[0] = t.x; uu[1] = t.y; uu[2] = t.z; uu[3] = t.w;
    } else {
        #pragma unroll
        for (int q = 0; q < 4; ++q) uu[q] = (i0 + q < m) ? ub[i0 + q] : 0.f;
    }
    int   pq[5] = {pp.x, pp.y, pp.z, pp.w, p5};
    float xq[5] = {xx.x, xx.y, xx.z, xx.w, x5};
    float sv[5];
    #pragma unroll
    for (int q = 0; q < 5; ++q)
        sv[q] = (pq[q] >= 0) ? vb[pq[q]] : nn(xq[q]);

    float wv[4], rv[4];
    float acc = 0.f;
    #pragma unroll
    for (int q = 0; q < 4; ++q) {
        float w = sp_w(uu[q]);
        float r = sv[q + 1] - sv[q];
        wv[q] = w; rv[q] = r;
        if (i0 + q < m) acc += w * w * r * r;
    }
    if (i0 + 4 <= m) {
        *reinterpret_cast<float4*>(wb + i0) = make_float4(wv[0], wv[1], wv[2], wv[3]);
        *reinterpret_cast<float4*>(rb + i0) = make_float4(rv[0], rv[1], rv[2], rv[3]);
    } else {
        #pragma unroll
        for (int q = 0; q < 4; ++q)
            if (i0 + q < m) { wb[i0 + q] = wv[q]; rb[i0 + q] = rv[q]; }
    }
    float s = blockReduceSum(acc);
    if (threadIdx.x == 0) atomicAdd(&phi[b], s);
}

extern "C" void kernel_launch(void* const* d_in, const int* in_sizes, int n_in,
                              void* d_out, int out_size, void* d_ws, size_t ws_size,
                              hipStream_t stream) {
    const float* u  = (const float*)d_in[0];  // [B, n-1]
    const float* x  = (const float*)d_in[1];  // [B, n]
    const int* idx  = (const int*)d_in[2];    // [K]

    const int B = 16;
    const int n = in_sizes[1] / B;   // 262144
    const int m = n - 1;             // 262143
    const int K = in_sizes[2];       // 131072
    const int NK = B * K;            // 2097152
    const int GRID = NK / CHUNK;     // 512 blocks = 2 per CU

    float* out   = (float*)d_out;
    float* phi   = out;                         // [B]
    float* v_out = out + B;                     // [B,K]
    float* r_out = v_out + (size_t)B * K;       // [B,m]
    float* w_out = r_out + (size_t)B * m;       // [B,m]

    char* ws = (char*)d_ws;
    unsigned long long* slotD = (unsigned long long*)ws;  ws += sizeof(unsigned long long) * 2 * GRID * 4;
    unsigned long long* slotK = (unsigned long long*)ws;  ws += sizeof(unsigned long long) * 2 * 2 * GRID;
    int* pos = (int*)ws;                                  ws += sizeof(int) * (size_t)n;

    hipMemsetAsync(slotD, 0, sizeof(unsigned long long) * (2 * GRID * 4 + 2 * 2 * GRID), stream);
    hipMemsetAsync(pos, 0xFF, sizeof(int) * (size_t)n, stream);  // -1

    k_scatter<<<(K + 255) / 256, 256, 0, stream>>>(idx, pos, K);

    k_cg_pers<<<GRID, CGBLK, 0, stream>>>(idx, u, x, v_out, phi,
                                          slotD, slotK, n, K, B, GRID);

    k_final<<<dim3((m + 1023) / 1024, B), 256, 0, stream>>>(u, x, pos, v_out,
                                                            w_out, r_out, phi, n, K);
}